// Round 12
// baseline (62.826 us; speedup 1.0000x reference)
//
#include <hip/hip_runtime.h>

// Problem constants
constexpr int B    = 8;
constexpr int N    = 4096;
constexpr int CIN  = 6;
constexpr int NC   = 3;
constexpr int NP   = 1024;
constexpr int C0   = CIN + NC;   // 9
constexpr int M1   = 64;
constexpr int M2   = 64;
constexpr int M3   = 128;
constexpr int NPTS = B * NP;     // 8192
constexpr int NPB  = 32;         // partial blocks per channel
constexpr float EPS = 1e-5f;

constexpr int GRID = 256;        // 1 block/CU -> trivially co-resident
constexpr int T    = 256;

typedef float f4 __attribute__((ext_vector_type(4)));

// d_out layout: [grouped_xyz zeros: 6 MB] ++ [pooled: B*M3*NP]
constexpr int GZ_ELEMS = B * NP * 64 * 3;   // 1,572,864 floats
constexpr int GZ_F4    = GZ_ELEMS / 4;      // 393,216 float4

// d_ws layout (floats)
constexpr size_t Y1_OFF  = 0;
constexpr size_t Y2_OFF  = Y1_OFF + (size_t)M1 * NPTS;
constexpr size_t Y3_OFF  = Y2_OFF + (size_t)M2 * NPTS;
constexpr size_t PS1_OFF = Y3_OFF + (size_t)M3 * NPTS;
constexpr size_t PQ1_OFF = PS1_OFF + M1 * NPB;
constexpr size_t PS2_OFF = PQ1_OFF + M1 * NPB;
constexpr size_t PQ2_OFF = PS2_OFF + M2 * NPB;
constexpr size_t PS3_OFF = PQ2_OFF + M2 * NPB;
constexpr size_t PQ3_OFF = PS3_OFF + M3 * NPB;
constexpr size_t BAR_OFF = PQ3_OFF + M3 * NPB;
// per barrier (512 uints): +x*32 arrive[x] (x=0..7), +256 master

// ---- node 1: zero the grid-barrier counters ----
__global__ void k0_init(unsigned* __restrict__ bar) {
    int t = threadIdx.x;
#pragma unroll
    for (int i = 0; i < 6; ++i) bar[i * 256 + t] = 0u;   // 1536 uints
}

// ---- device-scope write-through store (global_store ... sc1): lands in the
// shared memory-side cache, visible to all XCDs once vmcnt drains. ----
__device__ inline void st_dev(float* p, float v) {
    __hip_atomic_store(p, v, __ATOMIC_RELAXED, __HIP_MEMORY_SCOPE_AGENT);
}

__device__ inline unsigned xcc_id() {
    unsigned x;
    asm volatile("s_getreg_b32 %0, hwreg(HW_REG_XCC_ID)" : "=s"(x));
    return x & 7u;
}

// ---- fence-free grid barrier: NO release, NO acquire, no L2 walks.
// Cross-block data was stored with sc1 (write-through; device-visible once
// vmcnt==0, which __syncthreads guarantees before the arrival RMW). Readers'
// caches cannot hold stale copies: those regions are only ever written via
// sc1 (never through a reader L2) and kernel-entry acquire invalidated any
// prior-replay lines. Arrival: distributed per-XCD counters (RELAXED RMW at
// the coherence point); per-XCD leader spins on the sum, then master++
// (RELAXED); followers poll master != 0.
__device__ inline void grid_bar(unsigned* __restrict__ bar, int bi) {
    __syncthreads();   // exec sync + vmcnt(0) drain of the sc1 stores
    if (threadIdx.x == 0) {
        unsigned* base   = bar + bi * 512;
        unsigned* master = base + 256;
        unsigned  x      = xcc_id();
        unsigned  e = __hip_atomic_fetch_add(base + x * 32, 1u, __ATOMIC_RELAXED,
                                             __HIP_MEMORY_SCOPE_AGENT);
        long tries = 0;
        if (e == 0) {   // XCD leader
            for (;;) {
                unsigned s = 0;
#pragma unroll
                for (int i = 0; i < 8; ++i)
                    s += __hip_atomic_load(base + i * 32, __ATOMIC_RELAXED,
                                           __HIP_MEMORY_SCOPE_AGENT);
                if (s >= (unsigned)GRID) break;
                __builtin_amdgcn_s_sleep(2);
                if (++tries > (1L << 26)) break;   // safety valve
            }
            __hip_atomic_fetch_add(master, 1u, __ATOMIC_RELAXED,
                                   __HIP_MEMORY_SCOPE_AGENT);
        }
        tries = 0;
        while (__hip_atomic_load(master, __ATOMIC_RELAXED,
                                 __HIP_MEMORY_SCOPE_AGENT) == 0u) {
            __builtin_amdgcn_s_sleep(2);
            if (++tries > (1L << 26)) break;
        }
    }
    __syncthreads();
}

// ---- deterministic per-block partial sums (OC channels), sc1 stores ----
template <int OC>
__device__ inline void emit_partials(const float (&acc)[OC], int o0, int pb,
                                     float* __restrict__ ps, float* __restrict__ pq) {
    __shared__ float rs[OC][4], rq[OC][4];
    __syncthreads();   // guard shared reuse
    float sv[OC], qv[OC];
#pragma unroll
    for (int o = 0; o < OC; ++o) { sv[o] = acc[o]; qv[o] = acc[o] * acc[o]; }
#pragma unroll
    for (int off = 32; off; off >>= 1) {
#pragma unroll
        for (int o = 0; o < OC; ++o) {
            sv[o] += __shfl_down(sv[o], off, 64);
            qv[o] += __shfl_down(qv[o], off, 64);
        }
    }
    int lane = threadIdx.x & 63, w = threadIdx.x >> 6;
    if (lane == 0) {
#pragma unroll
        for (int o = 0; o < OC; ++o) { rs[o][w] = sv[o]; rq[o][w] = qv[o]; }
    }
    __syncthreads();
    if (threadIdx.x < OC) {
        int o = threadIdx.x;
        float s = rs[o][0] + rs[o][1] + rs[o][2] + rs[o][3];
        float q = rq[o][0] + rq[o][1] + rq[o][2] + rq[o][3];
        st_dev(&ps[(o0 + o) * NPB + pb], s);
        st_dev(&pq[(o0 + o) * NPB + pb], q);
    }
}

// ---- fold 64-channel partials into per-channel A,B (threads 0..63) ----
__device__ inline void fold_AB64(const float* __restrict__ ps, const float* __restrict__ pq,
                                 const float* __restrict__ gamma, const float* __restrict__ beta,
                                 float* __restrict__ sAB) {
    int t = threadIdx.x;
    if (t < 64) {
        float s = 0.f, q = 0.f;
#pragma unroll 8
        for (int i = 0; i < NPB; ++i) { s += ps[t * NPB + i]; q += pq[t * NPB + i]; }
        float inv_n = 1.0f / (float)NPTS;
        float mean = s * inv_n;
        float var  = q * inv_n - mean * mean;
        float A = gamma[t] * rsqrtf(var + EPS);
        sAB[2 * t]     = A;
        sAB[2 * t + 1] = beta[t] - mean * A;
    }
}

// ---- the fused persistent kernel (256 blocks, all blocks work every stage) ----
__global__ __launch_bounds__(T, 2)
void k_fused(const float* __restrict__ points,
             const float* __restrict__ onehot,
             const int*   __restrict__ idx,
             const float* __restrict__ w1,
             const float* __restrict__ g1, const float* __restrict__ b1,
             const float* __restrict__ w2,
             const float* __restrict__ g2, const float* __restrict__ b2,
             const float* __restrict__ w3,
             const float* __restrict__ g3, const float* __restrict__ b3,
             float* __restrict__ ws, float* __restrict__ out) {
    float* y1  = ws + Y1_OFF;
    float* y2  = ws + Y2_OFF;
    float* y3  = ws + Y3_OFF;
    float* ps1 = ws + PS1_OFF;  float* pq1 = ws + PQ1_OFF;
    float* ps2 = ws + PS2_OFF;  float* pq2 = ws + PQ2_OFF;
    float* ps3 = ws + PS3_OFF;  float* pq3 = ws + PQ3_OFF;
    unsigned* bar = (unsigned*)(ws + BAR_OFF);

    __shared__ float wsb[16 * 64];  // weight slice (stage 3 is the largest user)
    __shared__ float sAB[2 * 64];   // BN coeffs for stages 2/3
    __shared__ float sAB4[8];       // BN coeffs for stage 4 (4 channels)

    int t = threadIdx.x, blk = blockIdx.x;

    // ------- stage 1: zero-fill gz (nt) + gather + GEMM1 + partials -------
    {
        f4 z = {0.f, 0.f, 0.f, 0.f};
        f4* g = (f4*)out + (size_t)blk * (GZ_F4 / GRID) + t;
#pragma unroll
        for (int i = 0; i < GZ_F4 / GRID / 256; ++i)   // 6 stores
            __builtin_nontemporal_store(z, &g[i * 256]);

        int ob = blk & 7, pb = blk >> 3, o0 = ob * 8;
        int p  = pb * 256 + t;
        int b  = p >> 10;
        int pp = p & (NP - 1);
        int n  = idx[b * NP + pp];
        float f[C0];
#pragma unroll
        for (int c = 0; c < CIN; ++c) f[c] = points[((size_t)b * CIN + c) * N + n];
#pragma unroll
        for (int c = 0; c < NC; ++c)  f[CIN + c] = onehot[b * NC + c];
        float acc[8];
#pragma unroll
        for (int o = 0; o < 8; ++o) {
            float a = 0.f;
#pragma unroll
            for (int c = 0; c < C0; ++c) a += w1[(o0 + o) * C0 + c] * f[c];
            acc[o] = a;
            st_dev(&y1[(size_t)(o0 + o) * NPTS + p], a);
        }
        emit_partials<8>(acc, o0, pb, ps1, pq1);
    }
    grid_bar(bar, 0);

    // ------- stage 2: BN1+ReLU -> GEMM2 (8 out-ch/block) + partials -------
    {
        int ob = blk & 7, pb = blk >> 3, o0 = ob * 8;
        fold_AB64(ps1, pq1, g1, b1, sAB);
        for (int i = t; i < 512; i += 256) wsb[i] = w2[o0 * 64 + i];
        __syncthreads();
        int p = pb * 256 + t;
        float acc[8] = {0.f, 0.f, 0.f, 0.f, 0.f, 0.f, 0.f, 0.f};
        for (int ch = 0; ch < 64; ch += 16) {
            float x[16];
#pragma unroll
            for (int j = 0; j < 16; ++j) {
                int c = ch + j;
                float v = y1[(size_t)c * NPTS + p] * sAB[2 * c] + sAB[2 * c + 1];
                x[j] = fmaxf(v, 0.f);
            }
#pragma unroll
            for (int o = 0; o < 8; ++o) {
                float a = 0.f;
#pragma unroll
                for (int j = 0; j < 16; ++j) a += wsb[o * 64 + ch + j] * x[j];
                acc[o] += a;
            }
        }
#pragma unroll
        for (int o = 0; o < 8; ++o)
            st_dev(&y2[(size_t)(o0 + o) * NPTS + p], acc[o]);
        emit_partials<8>(acc, o0, pb, ps2, pq2);
    }
    grid_bar(bar, 1);

    // ------- stage 3: BN2+ReLU -> GEMM3 (16 out-ch/block) + partials -------
    {
        int ob = blk & 7, pb = blk >> 3, o0 = ob * 16;
        fold_AB64(ps2, pq2, g2, b2, sAB);
        __syncthreads();
        for (int i = t; i < 1024; i += 256) wsb[i] = w3[o0 * 64 + i];
        __syncthreads();
        int p = pb * 256 + t;
        float acc[16];
#pragma unroll
        for (int o = 0; o < 16; ++o) acc[o] = 0.f;
        for (int ch = 0; ch < 64; ch += 16) {
            float x[16];
#pragma unroll
            for (int j = 0; j < 16; ++j) {
                int c = ch + j;
                float v = y2[(size_t)c * NPTS + p] * sAB[2 * c] + sAB[2 * c + 1];
                x[j] = fmaxf(v, 0.f);
            }
#pragma unroll
            for (int o = 0; o < 16; ++o) {
                float a = 0.f;
#pragma unroll
                for (int j = 0; j < 16; ++j) a += wsb[o * 64 + ch + j] * x[j];
                acc[o] += a;
            }
        }
#pragma unroll
        for (int o = 0; o < 16; ++o)
            st_dev(&y3[(size_t)(o0 + o) * NPTS + p], acc[o]);
        emit_partials<16>(acc, o0, pb, ps3, pq3);
    }
    grid_bar(bar, 2);

    // ------- stage 4: BN3+ReLU, write pooled (4 rows per block, nt) -------
    {
        int r0 = blk * 4;              // rows r0..r0+3 of [B*M3][NP]
        int c0 = r0 & (M3 - 1);        // 4-aligned, no wrap
        int bb = r0 >> 7;
        if (t < 128) {
            int j  = t >> 5;           // channel c0+j
            int ch = c0 + j;
            int i  = t & 31;
            float s = ps3[ch * NPB + i];
            float q = pq3[ch * NPB + i];
#pragma unroll
            for (int off = 16; off; off >>= 1) {
                s += __shfl_down(s, off, 32);
                q += __shfl_down(q, off, 32);
            }
            if ((t & 31) == 0) {
                float inv_n = 1.0f / (float)NPTS;
                float mean = s * inv_n;
                float var  = q * inv_n - mean * mean;
                float A = g3[ch] * rsqrtf(var + EPS);
                sAB4[2 * j]     = A;
                sAB4[2 * j + 1] = b3[ch] - mean * A;
            }
        }
        __syncthreads();
        f4* out4 = (f4*)(out + GZ_ELEMS);
#pragma unroll
        for (int j = 0; j < 4; ++j) {
            float A = sAB4[2 * j], Bb = sAB4[2 * j + 1];
            const float4 v = ((const float4*)(y3 + (size_t)(c0 + j) * NPTS + bb * NP))[t];
            f4 r;
            r.x = fmaxf(v.x * A + Bb, 0.f);
            r.y = fmaxf(v.y * A + Bb, 0.f);
            r.z = fmaxf(v.z * A + Bb, 0.f);
            r.w = fmaxf(v.w * A + Bb, 0.f);
            __builtin_nontemporal_store(r, &out4[(size_t)(r0 + j) * 256 + t]);
        }
    }
}

extern "C" void kernel_launch(void* const* d_in, const int* in_sizes, int n_in,
                              void* d_out, int out_size, void* d_ws, size_t ws_size,
                              hipStream_t stream) {
    const float* points = (const float*)d_in[1];
    const float* onehot = (const float*)d_in[2];
    const int*   idx    = (const int*)d_in[3];
    const float* w1 = (const float*)d_in[4];
    const float* g1 = (const float*)d_in[5];
    const float* b1 = (const float*)d_in[6];
    const float* w2 = (const float*)d_in[7];
    const float* g2 = (const float*)d_in[8];
    const float* b2 = (const float*)d_in[9];
    const float* w3 = (const float*)d_in[10];
    const float* g3 = (const float*)d_in[11];
    const float* b3 = (const float*)d_in[12];

    float* ws  = (float*)d_ws;
    unsigned* bar = (unsigned*)(ws + BAR_OFF);

    k0_init<<<1, 256, 0, stream>>>(bar);
    k_fused<<<GRID, T, 0, stream>>>(points, onehot, idx,
                                    w1, g1, b1, w2, g2, b2, w3, g3, b3,
                                    ws, (float*)d_out);
}